// Round 11
// baseline (4181.380 us; speedup 1.0000x reference)
//
#include <hip/hip_runtime.h>
#include <stdint.h>

// ===================== Round 11 =====================
// R10 data path (register-direct h via pi-packed W2, swapped GEMM1 /
// unswapped GEMM2, W via global_load_lds) reorganized into 512 blocks
// x 4 waves = 2 INDEPENDENT barrier groups per CU (dephasing overlap).
// LDS/block 74K: W1 dbuf-2 16K + W2 ring-3 24K + xs 32K (unpadded,
// XOR-swizzled byte^((row&7)<<4)) + b1s 2K; b2 in registers; no hst.
// Per-chunk work unchanged (32 MFMA/wave); 16 barriers/eval/block.
// Predict: 1150-1500us if lockstep theory right (MfmaUtil 40-55);
// flat ~2100 falsifies -> intra-wave latency next. absmax 0.03125.
// ====================================================

typedef _Float16 half8 __attribute__((ext_vector_type(8)));
typedef float f32x4 __attribute__((ext_vector_type(4)));
typedef __attribute__((address_space(3))) char lchar;
typedef __attribute__((address_space(1))) char gchar;

static __device__ __forceinline__ void gload_lds16(const void* g, void* l) {
  __builtin_amdgcn_global_load_lds((const gchar*)g, (lchar*)l, 16, 0, 0);
}

static __device__ __forceinline__ unsigned short f2h(float x) {
  union { _Float16 h; unsigned short u; } cv;
  cv.h = (_Float16)x;
  return cv.u;
}
static __device__ __forceinline__ float h2f(unsigned short u) {
  union { unsigned short u; _Float16 h; } cv;
  cv.u = u;
  return (float)cv.h;
}
static __device__ __forceinline__ uint64_t pack4(float a, float b, float c, float d) {
  union { _Float16 h[4]; uint64_t q; } cv;
  cv.h[0] = (_Float16)a; cv.h[1] = (_Float16)b;
  cv.h[2] = (_Float16)c; cv.h[3] = (_Float16)d;
  return cv.q;
}

// xs swizzle: row-major [32 rows][128 feats] fp16, 256B rows, no pad;
// byte ^= ((row&7)<<4) spreads the stride-256B column reads across banks.
static __device__ __forceinline__ int xs_off(int r, int f) {
  return (r * 256 + f * 2) ^ ((r & 7) << 4);
}

// Prepack (identical to R10): 16 chunks of 32 hid, chunk c at wp+c*16384:
//  [0,8K): W1T A-frags (swapped GEMM1), f = T*4+ks, natural k.
//  [8K,16K): W2 B-frags (unswapped GEMM2), f = 8+O, pi-permuted k:
//            pi(g,j) = (j<4 ? 4g+j : 16+4g+(j-4)) -- matches GEMM1 C/D
//            reg order so h feeds GEMM2's A operand in registers.
__global__ void pack_w(const float* __restrict__ W1, const float* __restrict__ W2,
                       unsigned short* __restrict__ wp) {
  int id = blockIdx.x * 256 + threadIdx.x;  // 0..16383
  int lane = id & 63, fid = (id >> 6) & 255;
  int g = lane >> 4, lm = lane & 15;
  int c = fid >> 4, f = fid & 15;
  if (f < 8) {
    int T = f >> 2, ks = f & 3;
    int hid = c * 32 + T * 16 + lm;
#pragma unroll
    for (int j = 0; j < 8; ++j) {
      int kin = ks * 32 + g * 8 + j;
      wp[fid * 512 + lane * 8 + j] = f2h(W1[kin * 512 + hid]);
    }
  } else {
    int O = f - 8;
    int of = O * 16 + lm;
#pragma unroll
    for (int j = 0; j < 8; ++j) {
      int khl = (j < 4) ? (4 * g + j) : (16 + 4 * g + (j - 4));  // pi(g,j)
      wp[fid * 512 + lane * 8 + j] = f2h(W2[(c * 32 + khl) * 128 + of]);
    }
  }
}

__global__ __launch_bounds__(256, 2) void node_rk4(
    const float* __restrict__ x0, const float* __restrict__ b1,
    const float* __restrict__ b2, const unsigned short* __restrict__ wp,
    float* __restrict__ out) {
  // 74 KB LDS -> 2 blocks/CU (two independent barrier groups).
  __shared__ char W1b[2][8192];
  __shared__ char W2b[3][8192];
  __shared__ __align__(16) char xsm[4][8192];  // per-wave 32x128 fp16, swizzled
  __shared__ float b1s[512];

  const int tid = threadIdx.x;
  const int w = tid >> 6, lane = tid & 63;
  const int g = lane >> 4, lm = lane & 15;
  char* xw = xsm[w];

  b1s[tid] = b1[tid];
  b1s[tid + 256] = b1[tid + 256];
  float b2v[8];
#pragma unroll
  for (int O = 0; O < 8; ++O) b2v[O] = b2[O * 16 + lm];

  // UNSWAPPED state: lane (g,lm) holds batch rows mt*16+4g+j, feat col
  // O*16+lm. xa fp32 accumulator, xbh fp16 step base.
  const int rbase = blockIdx.x * 128 + w * 32;
  f32x4 xa[2][8];
  ushort4 xbh[2][8];
#pragma unroll
  for (int mt = 0; mt < 2; ++mt)
#pragma unroll
    for (int O = 0; O < 8; ++O) {
      f32x4 v;
#pragma unroll
      for (int j = 0; j < 4; ++j)
        v[j] = x0[(rbase + mt * 16 + 4 * g + j) * 128 + O * 16 + lm];
      xa[mt][O] = v;
      ushort4 hq;
      hq.x = f2h(v[0]); hq.y = f2h(v[1]); hq.z = f2h(v[2]); hq.w = f2h(v[3]);
      xbh[mt][O] = hq;
#pragma unroll
      for (int j = 0; j < 4; ++j)
        *(unsigned short*)(xw + xs_off(mt * 16 + 4 * g + j, O * 16 + lm)) =
            (&hq.x)[j];
    }

  // Pre-loop: prefetch W1 chunk 0 into slot 0 (2 segs/wave of 8).
#pragma unroll
  for (int q = 0; q < 2; ++q) {
    int seg = w * 2 + q;
    gload_lds16((const char*)wp + seg * 1024 + lane * 16, W1b[0] + seg * 1024);
  }
  asm volatile("s_waitcnt vmcnt(0) lgkmcnt(0)" ::: "memory");
  __builtin_amdgcn_s_barrier();

#pragma unroll 1
  for (int it = 0; it < 80; ++it) {
    const int s = it & 3;
    const float wgt = (s == 0 || s == 3) ? (0.1f / 6.0f) : (0.1f / 3.0f);
    const float alph = (s < 2) ? 0.05f : 0.1f;

    // x^T B-frags for swapped GEMM1 (wave-private xs, swizzled reads).
    half8 X1[2][4];
#pragma unroll
    for (int nt = 0; nt < 2; ++nt)
#pragma unroll
      for (int ks = 0; ks < 4; ++ks)
        X1[nt][ks] =
            *(const half8*)(xw + xs_off(nt * 16 + lm, ks * 32 + g * 8));

    // Eval-start barrier: publishes W2 slot 0 (tail of prev eval done).
    __builtin_amdgcn_s_barrier();

    f32x4 yacc[2][8];
#pragma unroll
    for (int mt = 0; mt < 2; ++mt)
#pragma unroll
      for (int O = 0; O < 8; ++O) yacc[mt][O] = f32x4{0.f, 0.f, 0.f, 0.f};

    half8 hpk[2][2];  // [c&1][mt] pi-packed h A-frags (register-direct)

#pragma unroll
    for (int c = 0; c < 16; ++c) {
      // Prefetch (depth 1). W1 chunk c+1 -> slot (c+1)&1; W2 chunk c+1 ->
      // slot (c+1)%3. Iter 0 additionally primes W2(0) (slot 0, cleared by
      // the eval-start barrier); iter 15 preloads next eval's W1 chunk 0.
      if (c == 0) {
#pragma unroll
        for (int q = 0; q < 2; ++q) {
          int seg = w * 2 + q;
          gload_lds16((const char*)wp + 16384 + seg * 1024 + lane * 16,
                      W1b[1] + seg * 1024);
          gload_lds16((const char*)wp + 8192 + seg * 1024 + lane * 16,
                      W2b[0] + seg * 1024);
          gload_lds16((const char*)wp + 16384 + 8192 + seg * 1024 + lane * 16,
                      W2b[1] + seg * 1024);
        }
      } else if (c < 15) {
        const char* src = (const char*)wp + (c + 1) * 16384;
#pragma unroll
        for (int q = 0; q < 2; ++q) {
          int seg = w * 2 + q;
          gload_lds16(src + seg * 1024 + lane * 16, W1b[(c + 1) & 1] + seg * 1024);
          gload_lds16(src + 8192 + seg * 1024 + lane * 16,
                      W2b[(c + 1) % 3] + seg * 1024);
        }
      } else {
#pragma unroll
        for (int q = 0; q < 2; ++q) {
          int seg = w * 2 + q;
          gload_lds16((const char*)wp + seg * 1024 + lane * 16, W1b[0] + seg * 1024);
        }
      }

      __builtin_amdgcn_s_setprio(1);
      // GEMM2(c-1), unswapped: y += h(A regs) x W2-frag(B).
      if (c > 0) {
        const char* Wp = W2b[(c - 1) % 3];
#pragma unroll
        for (int O = 0; O < 8; ++O) {
          half8 w2f = *(const half8*)(Wp + O * 1024 + lane * 16);
          yacc[0][O] = __builtin_amdgcn_mfma_f32_16x16x32_f16(hpk[(c - 1) & 1][0], w2f,
                                                              yacc[0][O], 0, 0, 0);
          yacc[1][O] = __builtin_amdgcn_mfma_f32_16x16x32_f16(hpk[(c - 1) & 1][1], w2f,
                                                              yacc[1][O], 0, 0, 0);
        }
      }

      // GEMM1'(c), swapped: h[hid][batch] = W1T(A) x x^T(B).
      const char* Wb = W1b[c & 1];
      f32x4 hacc[2][2];  // [T][nt]
#pragma unroll
      for (int T = 0; T < 2; ++T)
#pragma unroll
        for (int nt = 0; nt < 2; ++nt) hacc[T][nt] = f32x4{0.f, 0.f, 0.f, 0.f};
#pragma unroll
      for (int T = 0; T < 2; ++T)
#pragma unroll
        for (int ks = 0; ks < 4; ++ks) {
          half8 wa = *(const half8*)(Wb + (T * 4 + ks) * 1024 + lane * 16);
          hacc[T][0] =
              __builtin_amdgcn_mfma_f32_16x16x32_f16(wa, X1[0][ks], hacc[T][0], 0, 0, 0);
          hacc[T][1] =
              __builtin_amdgcn_mfma_f32_16x16x32_f16(wa, X1[1][ks], hacc[T][1], 0, 0, 0);
        }
      __builtin_amdgcn_s_setprio(0);

      // bias+relu, pack into pi order [T0 j0..3 | T1 j0..3].
      f32x4 bb0 = *(const f32x4*)&b1s[c * 32 + 4 * g];
      f32x4 bb1 = *(const f32x4*)&b1s[c * 32 + 16 + 4 * g];
#pragma unroll
      for (int nt = 0; nt < 2; ++nt) {
        union { uint64_t q[2]; half8 h; } u;
        u.q[0] = pack4(fmaxf(hacc[0][nt][0] + bb0[0], 0.f),
                       fmaxf(hacc[0][nt][1] + bb0[1], 0.f),
                       fmaxf(hacc[0][nt][2] + bb0[2], 0.f),
                       fmaxf(hacc[0][nt][3] + bb0[3], 0.f));
        u.q[1] = pack4(fmaxf(hacc[1][nt][0] + bb1[0], 0.f),
                       fmaxf(hacc[1][nt][1] + bb1[1], 0.f),
                       fmaxf(hacc[1][nt][2] + bb1[2], 0.f),
                       fmaxf(hacc[1][nt][3] + bb1[3], 0.f));
        hpk[c & 1][nt] = u.h;
      }

      asm volatile("s_waitcnt vmcnt(0)" ::: "memory");
      __builtin_amdgcn_s_barrier();
    }

    // Tail GEMM2(15): W2 slot 15%3 == 0 (no write raced it this eval).
    {
      const char* Wp = W2b[0];
#pragma unroll
      for (int O = 0; O < 8; ++O) {
        half8 w2f = *(const half8*)(Wp + O * 1024 + lane * 16);
        yacc[0][O] =
            __builtin_amdgcn_mfma_f32_16x16x32_f16(hpk[1][0], w2f, yacc[0][O], 0, 0, 0);
        yacc[1][O] =
            __builtin_amdgcn_mfma_f32_16x16x32_f16(hpk[1][1], w2f, yacc[1][O], 0, 0, 0);
      }
    }

    // RK4 combine (unswapped); scatter next x_in into swizzled xs.
#pragma unroll
    for (int mt = 0; mt < 2; ++mt)
#pragma unroll
      for (int O = 0; O < 8; ++O) {
        f32x4 k = yacc[mt][O];
#pragma unroll
        for (int j = 0; j < 4; ++j) k[j] += b2v[O];
        xa[mt][O] += wgt * k;
        ushort4 hq;
        if (s == 3) {
          f32x4 v = xa[mt][O];
          hq.x = f2h(v[0]); hq.y = f2h(v[1]); hq.z = f2h(v[2]); hq.w = f2h(v[3]);
          xbh[mt][O] = hq;
        } else {
          ushort4 xq = xbh[mt][O];
          hq.x = f2h(h2f(xq.x) + alph * k[0]);
          hq.y = f2h(h2f(xq.y) + alph * k[1]);
          hq.z = f2h(h2f(xq.z) + alph * k[2]);
          hq.w = f2h(h2f(xq.w) + alph * k[3]);
        }
#pragma unroll
        for (int j = 0; j < 4; ++j)
          *(unsigned short*)(xw + xs_off(mt * 16 + 4 * g + j, O * 16 + lm)) =
              (&hq.x)[j];
      }
  }

#pragma unroll
  for (int mt = 0; mt < 2; ++mt)
#pragma unroll
    for (int O = 0; O < 8; ++O)
#pragma unroll
      for (int j = 0; j < 4; ++j)
        out[(rbase + mt * 16 + 4 * g + j) * 128 + O * 16 + lm] = xa[mt][O][j];
}

extern "C" void kernel_launch(void* const* d_in, const int* in_sizes, int n_in,
                              void* d_out, int out_size, void* d_ws, size_t ws_size,
                              hipStream_t stream) {
  const float* x0 = (const float*)d_in[0];
  const float* W1 = (const float*)d_in[1];
  const float* b1 = (const float*)d_in[2];
  const float* W2 = (const float*)d_in[3];
  const float* b2 = (const float*)d_in[4];
  float* out = (float*)d_out;

  unsigned short* wp = (unsigned short*)d_ws;  // 256 frags * 1KB = 256KB

  pack_w<<<64, 256, 0, stream>>>(W1, W2, wp);
  node_rk4<<<512, 256, 0, stream>>>(x0, b1, b2, wp, out);
}

// Round 12
// 3007.476 us; speedup vs baseline: 1.3903x; 1.3903x over previous
//
#include <hip/hip_runtime.h>
#include <stdint.h>

// ===================== Round 12 =====================
// R10 base (register-direct h via pi-packed W2; swapped GEMM1 /
// unswapped GEMM2; 256 blk x 8 waves) + REGISTER double-buffered W1
// frags: during chunk c, ds_read chunk c+1's 8 W1 frags into the
// alternate reg set while GEMM1(c) runs from regs and GEMM2(c-1)'s
// JIT W2 reads hide under it. W1/W2 split into separate ring-4 LDS
// buffers with staggered gload depth (W1@c+3, W2@c+2); end-of-iter
// vmcnt(3) certifies {W1(c+2), W2(c)} -- ring audit in comments.
// Predict: 1450-1700us, MfmaUtil 33-40, VGPR ~200 no scratch,
// absmax 0.03125 exactly.
// ====================================================

typedef _Float16 half8 __attribute__((ext_vector_type(8)));
typedef float f32x4 __attribute__((ext_vector_type(4)));
typedef __attribute__((address_space(3))) char lchar;
typedef __attribute__((address_space(1))) char gchar;

#define XSTR 136  // shorts per xs row (128 + 8 pad) = 272B

static __device__ __forceinline__ void gload_lds16(const void* g, void* l) {
  __builtin_amdgcn_global_load_lds((const gchar*)g, (lchar*)l, 16, 0, 0);
}

static __device__ __forceinline__ unsigned short f2h(float x) {
  union { _Float16 h; unsigned short u; } cv;
  cv.h = (_Float16)x;
  return cv.u;
}
static __device__ __forceinline__ float h2f(unsigned short u) {
  union { unsigned short u; _Float16 h; } cv;
  cv.u = u;
  return (float)cv.h;
}
static __device__ __forceinline__ uint64_t pack4(float a, float b, float c, float d) {
  union { _Float16 h[4]; uint64_t q; } cv;
  cv.h[0] = (_Float16)a; cv.h[1] = (_Float16)b;
  cv.h[2] = (_Float16)c; cv.h[3] = (_Float16)d;
  return cv.q;
}

// Prepack: TWO streams. W1T A-frag stream (swapped GEMM1, natural k):
//   frag (c, f=T*4+ks) at wp[(c*8+f)*512], lane l holds
//   A[m=hid c*32+T*16+(l&15)][k_in=ks*32+(l>>4)*8+j].
// W2 B-frag stream (unswapped GEMM2, pi-permuted k) at +65536 shorts:
//   frag (c, O) at wp[65536+(c*8+O)*512]; lane l slot j holds
//   B[k_hid=c*32+pi(g,j)][n=out O*16+(l&15)], pi(g,j)=(j<4?4g+j:16+4g+j-4)
//   -- matches GEMM1's C/D reg order so h feeds GEMM2's A operand in regs.
__global__ void pack_w(const float* __restrict__ W1, const float* __restrict__ W2,
                       unsigned short* __restrict__ wp) {
  int id = blockIdx.x * 256 + threadIdx.x;  // 0..16383
  int lane = id & 63, fid = (id >> 6) & 255;
  int g = lane >> 4, lm = lane & 15;
  int c = fid >> 4, f = fid & 15;
  if (f < 8) {
    int T = f >> 2, ks = f & 3;
    int hid = c * 32 + T * 16 + lm;
#pragma unroll
    for (int j = 0; j < 8; ++j) {
      int kin = ks * 32 + g * 8 + j;
      wp[(c * 8 + f) * 512 + lane * 8 + j] = f2h(W1[kin * 512 + hid]);
    }
  } else {
    int O = f - 8;
    int of = O * 16 + lm;
#pragma unroll
    for (int j = 0; j < 8; ++j) {
      int khl = (j < 4) ? (4 * g + j) : (16 + 4 * g + (j - 4));  // pi(g,j)
      wp[65536 + (c * 8 + O) * 512 + lane * 8 + j] = f2h(W2[(c * 32 + khl) * 128 + of]);
    }
  }
}

__global__ __launch_bounds__(512, 2) void node_rk4(
    const float* __restrict__ x0, const float* __restrict__ b1,
    const float* __restrict__ b2, const unsigned short* __restrict__ wp,
    float* __restrict__ out) {
  // LDS: W1 ring 32K + W2 ring 32K + xs 68K + biases 2.5K = 136,320 B.
  __shared__ char W1b[4][8192];
  __shared__ char W2b[4][8192];
  __shared__ __align__(16) unsigned short xs[8][32][XSTR];
  __shared__ float b1s[512];
  __shared__ float b2s[128];

  const int tid = threadIdx.x;
  const int w = tid >> 6, lane = tid & 63;
  const int g = lane >> 4, lm = lane & 15;

  b1s[tid] = b1[tid];
  if (tid < 128) b2s[tid] = b2[tid];

  const char* w1g = (const char*)wp;           // W1 frag stream, 128 KB
  const char* w2g = (const char*)wp + 131072;  // W2 frag stream, 128 KB

  // UNSWAPPED state: lane (g,lm) holds batch rows mt*16+4g+j, feat col
  // O*16+lm. xa fp32 accumulator, xbh fp16 step base.
  const int rbase = blockIdx.x * 256 + w * 32;
  f32x4 xa[2][8];
  ushort4 xbh[2][8];
#pragma unroll
  for (int mt = 0; mt < 2; ++mt)
#pragma unroll
    for (int O = 0; O < 8; ++O) {
      f32x4 v;
#pragma unroll
      for (int j = 0; j < 4; ++j)
        v[j] = x0[(rbase + mt * 16 + 4 * g + j) * 128 + O * 16 + lm];
      xa[mt][O] = v;
      ushort4 hq;
      hq.x = f2h(v[0]); hq.y = f2h(v[1]); hq.z = f2h(v[2]); hq.w = f2h(v[3]);
      xbh[mt][O] = hq;
      unsigned short* xr = &xs[w][mt * 16 + 4 * g][O * 16 + lm];
      xr[0] = hq.x; xr[XSTR] = hq.y; xr[2 * XSTR] = hq.z; xr[3 * XSTR] = hq.w;
    }

  // Prologue: issue W1(0); W1(1),W2(0); W1(2),W2(1)  (1KB gload per wave
  // per chunk-half: wave w owns seg w of 8). Then vmcnt(2) certifies the
  // oldest 3 {W1(0),W1(1),W2(0)}; barrier; ds_read W1(0) -> reg set 0.
  gload_lds16(w1g + 0 * 8192 + w * 1024 + lane * 16, W1b[0] + w * 1024);
  gload_lds16(w1g + 1 * 8192 + w * 1024 + lane * 16, W1b[1] + w * 1024);
  gload_lds16(w2g + 0 * 8192 + w * 1024 + lane * 16, W2b[0] + w * 1024);
  gload_lds16(w1g + 2 * 8192 + w * 1024 + lane * 16, W1b[2] + w * 1024);
  gload_lds16(w2g + 1 * 8192 + w * 1024 + lane * 16, W2b[1] + w * 1024);
  asm volatile("s_waitcnt vmcnt(2) lgkmcnt(0)" ::: "memory");
  __builtin_amdgcn_s_barrier();

  half8 w1r[2][8];  // double-buffered W1 frag register sets
#pragma unroll
  for (int f = 0; f < 8; ++f)
    w1r[0][f] = *(const half8*)(W1b[0] + f * 1024 + lane * 16);

#pragma unroll 1
  for (int it = 0; it < 80; ++it) {
    const int s = it & 3;
    const float wgt = (s == 0 || s == 3) ? (0.1f / 6.0f) : (0.1f / 3.0f);
    const float alph = (s < 2) ? 0.05f : 0.1f;

    // x^T B-frags for swapped GEMM1 (wave-private xs), held all eval.
    half8 X1[2][4];
#pragma unroll
    for (int nt = 0; nt < 2; ++nt)
#pragma unroll
      for (int ks = 0; ks < 4; ++ks)
        X1[nt][ks] = *(const half8*)&xs[w][nt * 16 + lm][ks * 32 + g * 8];

    f32x4 yacc[2][8];
#pragma unroll
    for (int mt = 0; mt < 2; ++mt)
#pragma unroll
      for (int O = 0; O < 8; ++O) yacc[mt][O] = f32x4{0.f, 0.f, 0.f, 0.f};

    half8 hpk[2][2];  // [c&1][mt] pi-packed h A-frags

    // Steady-state ring audit (c = iter index, chunk ids mod 16):
    //  top of c issues: gload W1(c+3) -> W1b[(c+3)&3], W2(c+2) -> W2b[(c+2)&3]
    //  during c: ds_read W1(c+1) (slot certified at end of c-1),
    //            JIT ds_read W2(c-1) for GEMM2(c-1) (certified end of c-2)
    //  end of c: vmcnt(3) certifies {W2(c), W1(c+2)} (oldest 2 of 5), barrier.
    //  W1 slot (c+3)&3 overwrite vs last read (W1(c-1) during c-2): 2 barriers.
    //  W2 slot (c+2)&3 overwrite vs last read (W2(c-2) during c-1): 1 barrier.
#pragma unroll
    for (int c = 0; c < 16; ++c) {
      // top: gload issues (wrap chunk index across evals; weights invariant)
      gload_lds16(w1g + ((c + 3) & 15) * 8192 + w * 1024 + lane * 16,
                  W1b[(c + 3) & 3] + w * 1024);
      gload_lds16(w2g + ((c + 2) & 15) * 8192 + w * 1024 + lane * 16,
                  W2b[(c + 2) & 3] + w * 1024);

      // prefetch W1(c+1) frags into alternate reg set (consumed next iter)
#pragma unroll
      for (int f = 0; f < 8; ++f)
        w1r[(c + 1) & 1][f] =
            *(const half8*)(W1b[(c + 1) & 3] + f * 1024 + lane * 16);

      __builtin_amdgcn_s_setprio(1);
      // GEMM1'(c), swapped: h[hid][batch] = W1T(A regs) x x^T(B regs).
      f32x4 hacc[2][2];  // [T][nt]
#pragma unroll
      for (int T = 0; T < 2; ++T)
#pragma unroll
        for (int nt = 0; nt < 2; ++nt) hacc[T][nt] = f32x4{0.f, 0.f, 0.f, 0.f};
#pragma unroll
      for (int T = 0; T < 2; ++T)
#pragma unroll
        for (int ks = 0; ks < 4; ++ks) {
          half8 wa = w1r[c & 1][T * 4 + ks];
          hacc[T][0] =
              __builtin_amdgcn_mfma_f32_16x16x32_f16(wa, X1[0][ks], hacc[T][0], 0, 0, 0);
          hacc[T][1] =
              __builtin_amdgcn_mfma_f32_16x16x32_f16(wa, X1[1][ks], hacc[T][1], 0, 0, 0);
        }

      // GEMM2(c-1), unswapped: y += h(A regs) x W2-frag(B, JIT LDS reads --
      // compiler hoists these under GEMM1's MFMA window).
      if (c > 0) {
        const char* Wp = W2b[(c - 1) & 3];
#pragma unroll
        for (int O = 0; O < 8; ++O) {
          half8 w2f = *(const half8*)(Wp + O * 1024 + lane * 16);
          yacc[0][O] = __builtin_amdgcn_mfma_f32_16x16x32_f16(hpk[(c - 1) & 1][0], w2f,
                                                              yacc[0][O], 0, 0, 0);
          yacc[1][O] = __builtin_amdgcn_mfma_f32_16x16x32_f16(hpk[(c - 1) & 1][1], w2f,
                                                              yacc[1][O], 0, 0, 0);
        }
      }
      __builtin_amdgcn_s_setprio(0);

      // bias+relu, pack into pi order [T0 j0..3 | T1 j0..3].
      f32x4 bb0 = *(const f32x4*)&b1s[c * 32 + 4 * g];
      f32x4 bb1 = *(const f32x4*)&b1s[c * 32 + 16 + 4 * g];
#pragma unroll
      for (int nt = 0; nt < 2; ++nt) {
        union { uint64_t q[2]; half8 h; } u;
        u.q[0] = pack4(fmaxf(hacc[0][nt][0] + bb0[0], 0.f),
                       fmaxf(hacc[0][nt][1] + bb0[1], 0.f),
                       fmaxf(hacc[0][nt][2] + bb0[2], 0.f),
                       fmaxf(hacc[0][nt][3] + bb0[3], 0.f));
        u.q[1] = pack4(fmaxf(hacc[1][nt][0] + bb1[0], 0.f),
                       fmaxf(hacc[1][nt][1] + bb1[1], 0.f),
                       fmaxf(hacc[1][nt][2] + bb1[2], 0.f),
                       fmaxf(hacc[1][nt][3] + bb1[3], 0.f));
        hpk[c & 1][nt] = u.h;
      }

      asm volatile("s_waitcnt vmcnt(3)" ::: "memory");
      __builtin_amdgcn_s_barrier();
    }

    // Tail GEMM2(15): W2b[3] certified by end-of-15 vmcnt; next eval's
    // top-0 issues touch W1b[3]/W2b[2], not W2b[3].
    {
      const char* Wp = W2b[3];
#pragma unroll
      for (int O = 0; O < 8; ++O) {
        half8 w2f = *(const half8*)(Wp + O * 1024 + lane * 16);
        yacc[0][O] =
            __builtin_amdgcn_mfma_f32_16x16x32_f16(hpk[1][0], w2f, yacc[0][O], 0, 0, 0);
        yacc[1][O] =
            __builtin_amdgcn_mfma_f32_16x16x32_f16(hpk[1][1], w2f, yacc[1][O], 0, 0, 0);
      }
    }

    // RK4 combine (unswapped); scatter next x_in into xs (4 b16 per tile).
#pragma unroll
    for (int mt = 0; mt < 2; ++mt)
#pragma unroll
      for (int O = 0; O < 8; ++O) {
        float bb2 = b2s[O * 16 + lm];
        f32x4 k = yacc[mt][O];
#pragma unroll
        for (int j = 0; j < 4; ++j) k[j] += bb2;
        xa[mt][O] += wgt * k;
        ushort4 hq;
        if (s == 3) {
          f32x4 v = xa[mt][O];
          hq.x = f2h(v[0]); hq.y = f2h(v[1]); hq.z = f2h(v[2]); hq.w = f2h(v[3]);
          xbh[mt][O] = hq;
        } else {
          ushort4 xq = xbh[mt][O];
          hq.x = f2h(h2f(xq.x) + alph * k[0]);
          hq.y = f2h(h2f(xq.y) + alph * k[1]);
          hq.z = f2h(h2f(xq.z) + alph * k[2]);
          hq.w = f2h(h2f(xq.w) + alph * k[3]);
        }
        unsigned short* xr = &xs[w][mt * 16 + 4 * g][O * 16 + lm];
        xr[0] = hq.x; xr[XSTR] = hq.y; xr[2 * XSTR] = hq.z; xr[3 * XSTR] = hq.w;
      }
  }

#pragma unroll
  for (int mt = 0; mt < 2; ++mt)
#pragma unroll
    for (int O = 0; O < 8; ++O)
#pragma unroll
      for (int j = 0; j < 4; ++j)
        out[(rbase + mt * 16 + 4 * g + j) * 128 + O * 16 + lm] = xa[mt][O][j];
}

extern "C" void kernel_launch(void* const* d_in, const int* in_sizes, int n_in,
                              void* d_out, int out_size, void* d_ws, size_t ws_size,
                              hipStream_t stream) {
  const float* x0 = (const float*)d_in[0];
  const float* W1 = (const float*)d_in[1];
  const float* b1 = (const float*)d_in[2];
  const float* W2 = (const float*)d_in[3];
  const float* b2 = (const float*)d_in[4];
  float* out = (float*)d_out;

  unsigned short* wp = (unsigned short*)d_ws;  // 2 x 128KB frag streams

  pack_w<<<64, 256, 0, stream>>>(W1, W2, wp);
  node_rk4<<<256, 512, 0, stream>>>(x0, b1, b2, wp, out);
}